// Round 3
// baseline (264.012 us; speedup 1.0000x reference)
//
#include <hip/hip_runtime.h>

#define CHANNELS 3
#define HW 512
#define KS 15
#define GPAD 7
#define TILE 64
#define HT (TILE + 2 * GPAD)   // 78 mid rows (output tile + vertical halo)
#define MSTR 65                // mid LDS stride: odd -> all LDS access <=2-way bank aliasing (free)

// LDS = 78*65*4 = 20280 B -> 8 blocks/CU; 8 x 4 waves = 32 waves/CU (full).
// Per-item liveness ~32 VGPR -> fits the 64-VGPR cap of (256,8) without spill.
__global__ __launch_bounds__(256, 8)
void gauss_blur_kernel(const float* __restrict__ x,
                       const float* __restrict__ sigma,
                       float* __restrict__ out) {
    // Single LDS buffer: horizontally-filtered "mid" tile, 78 rows x 64 cols.
    __shared__ float mid_s[HT * MSTR];

    const int tid   = threadIdx.x;   // 0..255
    const int tileX = blockIdx.x;    // 0..7
    const int tileY = blockIdx.y;    // 0..7
    const int bc    = blockIdx.z;    // 0..B*C-1
    const int b     = bc / CHANNELS;

    // per-batch 1D Gaussian weights; wave-uniform -> pin to SGPRs
    // (v_fma_f32 sources one SGPR operand; frees 15 VGPRs).
    float w[KS];
    {
        const float s = sigma[b];
        const float inv_denom = 1.0f / (2.0f * s * s + 1e-8f);
        float g[KS];
        float sum = 0.0f;
        #pragma unroll
        for (int i = 0; i < KS; ++i) {
            const float d = (float)(i - GPAD);
            g[i] = __expf(-d * d * inv_denom);
            sum += g[i];
        }
        const float inv = 1.0f / sum;
        #pragma unroll
        for (int i = 0; i < KS; ++i)
            w[i] = __int_as_float(__builtin_amdgcn_readfirstlane(__float_as_int(g[i] * inv)));
    }

    const size_t plane = (size_t)HW * HW;
    const float* xp = x + (size_t)bc * plane;
    float* op       = out + (size_t)bc * plane;
    const int gx0 = tileX * TILE;          // first output col of tile
    const int gy0 = tileY * TILE - GPAD;   // first mid row (global)
    const bool xin = (tileX > 0) && (tileX < (HW / TILE) - 1);

    // ---- phase H: horizontal pass, global -> registers -> mid in LDS.
    // Item i -> (row r = i>>4, 4-col chunk q = i&15): window = 20 floats
    // [gx0+4q-8, gx0+4q+12) as 5 aligned float4. Lanes 0..15 of a wave cover ONE
    // row contiguously (16B/lane adjacent) -> perfectly coalesced global loads
    // issued throughout the phase. Window float m is tap t = m-1-o for output o
    // (uses m in [1,18]); acc[o] completes at m = o+15 -> early store to LDS. ----
    for (int i = tid; i < HT * 16; i += 256) {
        const int r  = i >> 4;
        const int q  = i & 15;
        const int gy = gy0 + r;
        float* dst = &mid_s[r * MSTR + 4 * q];
        if ((unsigned)gy >= (unsigned)HW) {
            // out-of-image row: zero-padded conv -> mid row is zero
            dst[0] = 0.0f; dst[1] = 0.0f; dst[2] = 0.0f; dst[3] = 0.0f;
            continue;
        }
        const int c0 = gx0 + 4 * q - 8;        // 16B-aligned window start
        const float* rowp = xp + (size_t)gy * HW + c0;
        float win[20];
        if (xin) {
            #pragma unroll
            for (int k = 0; k < 5; ++k) {
                const float4 v = *(const float4*)(rowp + 4 * k);
                win[4 * k + 0] = v.x; win[4 * k + 1] = v.y;
                win[4 * k + 2] = v.z; win[4 * k + 3] = v.w;
            }
        } else {
            #pragma unroll
            for (int m = 0; m < 20; ++m) {
                const int gc = c0 + m;
                win[m] = ((unsigned)gc < (unsigned)HW) ? rowp[m] : 0.0f;
            }
        }
        float acc[4] = {0.0f, 0.0f, 0.0f, 0.0f};
        #pragma unroll
        for (int m = 1; m <= 18; ++m) {
            const float v = win[m];
            const int lo = (m - 15) > 0 ? (m - 15) : 0;
            const int hi = (m - 1) < 3 ? (m - 1) : 3;
            #pragma unroll
            for (int o = lo; o <= hi; ++o)
                acc[o] = fmaf(w[m - 1 - o], v, acc[o]);   // tap t = m-1-o, ascending
            if (m >= 15) dst[m - 15] = acc[m - 15];       // acc[o] done at m = o+15
        }
    }
    __syncthreads();   // the only barrier in the kernel

    // ---- phase V: vertical pass from mid, accumulate on load; coalesced
    // 256B/wave stores. Lane layout: c = tid&63 (consecutive cols -> conflict-free
    // ds_read), r0 = (tid>>6)*16. Tap order identical to baseline. ----
    {
        const int c  = tid & (TILE - 1);
        const int r0 = (tid >> 6) * 16;
        float vacc[16];
        #pragma unroll
        for (int o = 0; o < 16; ++o) vacc[o] = 0.0f;
        #pragma unroll
        for (int j = 0; j < 30; ++j) {
            const float v = mid_s[(r0 + j) * MSTR + c];
            const int lo = (j - 14) > 0 ? (j - 14) : 0;
            const int hi = (j < 15) ? j : 15;
            #pragma unroll
            for (int o = lo; o <= hi; ++o)
                vacc[o] = fmaf(w[j - o], v, vacc[o]);
        }
        float* colp = op + (size_t)(tileY * TILE + r0) * HW + gx0 + c;
        #pragma unroll
        for (int o = 0; o < 16; ++o)
            colp[(size_t)o * HW] = vacc[o];
    }
}

extern "C" void kernel_launch(void* const* d_in, const int* in_sizes, int n_in,
                              void* d_out, int out_size, void* d_ws, size_t ws_size,
                              hipStream_t stream) {
    const float* x     = (const float*)d_in[0];
    const float* sigma = (const float*)d_in[1];
    float* out         = (float*)d_out;
    const int B = in_sizes[1];  // 32
    dim3 grid(HW / TILE, HW / TILE, B * CHANNELS);
    gauss_blur_kernel<<<grid, dim3(256, 1, 1), 0, stream>>>(x, sigma, out);
}

// Round 4
// 178.908 us; speedup vs baseline: 1.4757x; 1.4757x over previous
//
#include <hip/hip_runtime.h>

#define CHANNELS 3
#define HW 512
#define KS 15
#define GPAD 7
#define TILE_W 64
#define TILE_H 32
#define HT (TILE_H + 2 * GPAD)   // 46 staged input rows (tile + vertical halo)
#define IN_STR 81                // odd stride: hot LDS phases <=2-way aliasing (free)
#define WCOLS 20                 // 20 float4 = 80 staged cols [gx0-8, gx0+72)
#define NSTAGE (HT * WCOLS)      // 920 float4 stage items
#define WIN (16 + KS - 1)        // 30-tap window per 16-output chunk

// LDS = 46*81*4 = 14904 B -> 8 blocks/CU (8 x 4 waves = 32 waves/CU, full).
// launch_bounds(256,8): VGPR cap 64; hot-phase liveness ~24-32 VGPR, no spill.
__global__ __launch_bounds__(256, 8)
void gauss_blur_kernel(const float* __restrict__ x,
                       const float* __restrict__ sigma,
                       float* __restrict__ out) {
    // Single LDS buffer, reused in place:
    //   phase 0: input tile rows [gy0, gy0+46) x cols [gx0-8, gx0+72)  (46 x 80)
    //   phase 2: horizontal-pass result (mid) overwrites cols [0, 64)  (46 x 64)
    __shared__ float in_s[HT * IN_STR];

    const int tid   = threadIdx.x;   // 0..255
    const int tileX = blockIdx.x;    // 0..7
    const int tileY = blockIdx.y;    // 0..15
    const int bc    = blockIdx.z;    // 0..B*C-1
    const int b     = bc / CHANNELS;

    const size_t plane = (size_t)HW * HW;
    const float* xp = x + (size_t)bc * plane;
    float* op       = out + (size_t)bc * plane;
    const int gx0 = tileX * TILE_W;         // first output col of tile
    const int gy0 = tileY * TILE_H - GPAD;  // first staged row (global)
    const int ax0 = gx0 - 8;                // 16B-aligned staged-window start col

    // ---- phase 0a: ISSUE the staging burst — 4 independent float4 loads per
    // thread, no consumer in between (max MLP; this is what r2/r3 lost). ----
    float4 v[4];
    int   rr[4], qq[4];
    bool  ok[4];
    #pragma unroll
    for (int s = 0; s < 4; ++s) {
        const int i = tid + 256 * s;
        ok[s] = (i < NSTAGE);
        const int r = i / WCOLS;
        const int q = i - r * WCOLS;
        rr[s] = r; qq[s] = q;
        v[s] = make_float4(0.f, 0.f, 0.f, 0.f);
        if (ok[s]) {
            const int gy = gy0 + r;
            const int gc = ax0 + 4 * q;
            if ((unsigned)gy < (unsigned)HW) {
                const float* rowp = xp + (size_t)gy * HW;
                if (gc >= 0 && gc + 4 <= HW) {
                    v[s] = *(const float4*)(rowp + gc);
                } else {
                    if ((unsigned)(gc + 0) < (unsigned)HW) v[s].x = rowp[gc + 0];
                    if ((unsigned)(gc + 1) < (unsigned)HW) v[s].y = rowp[gc + 1];
                    if ((unsigned)(gc + 2) < (unsigned)HW) v[s].z = rowp[gc + 2];
                    if ((unsigned)(gc + 3) < (unsigned)HW) v[s].w = rowp[gc + 3];
                }
            }
        }
    }

    // ---- weights: computed while the staging loads are in flight (independent
    // of v[]); wave-uniform -> pin to SGPRs via readfirstlane. ----
    float w[KS];
    {
        const float s = sigma[b];
        const float inv_denom = 1.0f / (2.0f * s * s + 1e-8f);
        float g[KS];
        float sum = 0.0f;
        #pragma unroll
        for (int i = 0; i < KS; ++i) {
            const float d = (float)(i - GPAD);
            g[i] = __expf(-d * d * inv_denom);
            sum += g[i];
        }
        const float inv = 1.0f / sum;
        #pragma unroll
        for (int i = 0; i < KS; ++i)
            w[i] = __int_as_float(__builtin_amdgcn_readfirstlane(__float_as_int(g[i] * inv)));
    }

    // ---- phase 0b: drain loads into LDS ----
    #pragma unroll
    for (int s = 0; s < 4; ++s) {
        if (ok[s]) {
            float* d = &in_s[rr[s] * IN_STR + 4 * qq[s]];
            d[0] = v[s].x; d[1] = v[s].y; d[2] = v[s].z; d[3] = v[s].w;
        }
    }
    __syncthreads();

    // ---- phase 1: horizontal pass, LDS -> registers (accumulate on load).
    // Item tid -> (row r = tid>>2, 16-col chunk ch = tid&3); 184 items, 1 round.
    // Output local col oc = 16ch + o reads staged cols [oc+1, oc+30). Tap order
    // identical to baseline (ascending j, w[j-o]). ----
    float acc[16];
    #pragma unroll
    for (int o = 0; o < 16; ++o) acc[o] = 0.0f;
    const bool hwork = (tid < HT * 4);
    if (hwork) {
        const int r  = tid >> 2;
        const int ch = tid & 3;
        const float* src = &in_s[r * IN_STR + 16 * ch + 1];
        #pragma unroll
        for (int j = 0; j < WIN; ++j) {
            const float vv = src[j];
            const int lo = (j - (KS - 1)) > 0 ? (j - (KS - 1)) : 0;
            const int hi = (j < 15) ? j : 15;
            #pragma unroll
            for (int o = lo; o <= hi; ++o)
                acc[o] = fmaf(w[j - o], vv, acc[o]);
        }
    }
    __syncthreads();   // all LDS reads done before in-place overwrite

    // ---- phase 2: write mid back into the same LDS buffer (cols 0..63) ----
    if (hwork) {
        const int r  = tid >> 2;
        const int ch = tid & 3;
        float* dst = &in_s[r * IN_STR + 16 * ch];
        #pragma unroll
        for (int o = 0; o < 16; ++o) dst[o] = acc[o];
    }
    __syncthreads();

    // ---- phase 3: vertical pass from LDS, accumulate on load; coalesced
    // 256B/wave stores. c = tid&63 (2-way free ds_read), r0 = (tid>>6)*8. ----
    {
        const int c  = tid & (TILE_W - 1);
        const int r0 = (tid >> 6) * 8;
        float vacc[8];
        #pragma unroll
        for (int o = 0; o < 8; ++o) vacc[o] = 0.0f;
        #pragma unroll
        for (int j = 0; j < 8 + KS - 1; ++j) {     // 22 taps for 8 outputs
            const float vv = in_s[(r0 + j) * IN_STR + c];
            const int lo = (j - (KS - 1)) > 0 ? (j - (KS - 1)) : 0;
            const int hi = (j < 8) ? j : 7;
            #pragma unroll
            for (int o = lo; o <= hi; ++o)
                vacc[o] = fmaf(w[j - o], vv, vacc[o]);
        }
        float* colp = op + (size_t)(tileY * TILE_H + r0) * HW + gx0 + c;
        #pragma unroll
        for (int o = 0; o < 8; ++o)
            colp[(size_t)o * HW] = vacc[o];
    }
}

extern "C" void kernel_launch(void* const* d_in, const int* in_sizes, int n_in,
                              void* d_out, int out_size, void* d_ws, size_t ws_size,
                              hipStream_t stream) {
    const float* x     = (const float*)d_in[0];
    const float* sigma = (const float*)d_in[1];
    float* out         = (float*)d_out;
    const int B = in_sizes[1];  // 32
    dim3 grid(HW / TILE_W, HW / TILE_H, B * CHANNELS);
    gauss_blur_kernel<<<grid, dim3(256, 1, 1), 0, stream>>>(x, sigma, out);
}